// Round 8
// baseline (55998.425 us; speedup 1.0000x reference)
//
#include <hip/hip_runtime.h>

#define HH    100
#define G4    400
#define LSEQ  168
#define STEPS 48
#define NTICK 8066     // L0 at tick t (t<8064), L1 at tick t-1
#define SHP   112      // padded h stride (zeros beyond 100)
#define NXWH4 4032     // 4q * 144 rows * 7 chunks (Whh1-extras panel, float4)
#define NXW4  4928     // + 4q * 32 * 7 (Wih1-extras)  => 78,848 B total

__device__ __forceinline__ float sigmoidf_(float x) {
    return 1.0f / (1.0f + __expf(-x));
}
__device__ __forceinline__ float tanhf_(float x) {
    return 1.0f - 2.0f / (__expf(2.0f * x) + 1.0f);
}

// ---- asm blocks -----------------------------------------------------------
// Round-6 lesson: readlane costs ~7cy issue (wave-level gather), fmac 2cy.
// So amortize: each thread owns 4 rows x quarter-K: per k, 2 RL feed 8 fmacs.
// Lane-select is a wave-uniform SGPR (quarter base), legal for v_readlane.
// Blocks chain through "+v" accumulators -> no cross-block RL clustering
// (the rounds-1..4 spill cascade).

// 2 k-words, 4 main rows, 2 batches: 4 RL + 16 fmac.
#define KB2(c0_, c1_, wa0,wa1,wa2,wa3, wb0,wb1,wb2,wb3, lA_, lB_)              \
    asm("v_readlane_b32 %8, %12, %22\n\t"                                      \
        "v_readlane_b32 %9, %12, %23\n\t"                                      \
        "v_readlane_b32 %10, %13, %22\n\t"                                     \
        "v_readlane_b32 %11, %13, %23\n\t"                                     \
        "v_fmac_f32 %0, %8, %14\n\t"                                           \
        "v_fmac_f32 %1, %8, %15\n\t"                                           \
        "v_fmac_f32 %2, %8, %16\n\t"                                           \
        "v_fmac_f32 %3, %8, %17\n\t"                                           \
        "v_fmac_f32 %4, %9, %14\n\t"                                           \
        "v_fmac_f32 %5, %9, %15\n\t"                                           \
        "v_fmac_f32 %6, %9, %16\n\t"                                           \
        "v_fmac_f32 %7, %9, %17\n\t"                                           \
        "v_fmac_f32 %0, %10, %18\n\t"                                          \
        "v_fmac_f32 %1, %10, %19\n\t"                                          \
        "v_fmac_f32 %2, %10, %20\n\t"                                          \
        "v_fmac_f32 %3, %10, %21\n\t"                                          \
        "v_fmac_f32 %4, %11, %18\n\t"                                          \
        "v_fmac_f32 %5, %11, %19\n\t"                                          \
        "v_fmac_f32 %6, %11, %20\n\t"                                          \
        "v_fmac_f32 %7, %11, %21\n\t"                                          \
        : "+v"(aA0), "+v"(aA1), "+v"(aA2), "+v"(aA3),                          \
          "+v"(aB0), "+v"(aB1), "+v"(aB2), "+v"(aB3),                          \
          "=&s"(sg0), "=&s"(sg1), "=&s"(sg2), "=&s"(sg3)                       \
        : "v"(c0_), "v"(c1_),                                                  \
          "v"(wa0), "v"(wa1), "v"(wa2), "v"(wa3),                              \
          "v"(wb0), "v"(wb1), "v"(wb2), "v"(wb3),                              \
          "s"(lA_), "s"(lB_))

// 2 k-words, 2 extra rows, 2 batches: 4 RL + 8 fmac.
#define XB2(c0_, c1_, u0a, u1a, u0b, u1b, lA_, lB_)                            \
    asm("v_readlane_b32 %4, %8, %14\n\t"                                       \
        "v_readlane_b32 %5, %8, %15\n\t"                                       \
        "v_readlane_b32 %6, %9, %14\n\t"                                       \
        "v_readlane_b32 %7, %9, %15\n\t"                                       \
        "v_fmac_f32 %0, %4, %10\n\t"                                           \
        "v_fmac_f32 %1, %4, %11\n\t"                                           \
        "v_fmac_f32 %2, %5, %10\n\t"                                           \
        "v_fmac_f32 %3, %5, %11\n\t"                                           \
        "v_fmac_f32 %0, %6, %12\n\t"                                           \
        "v_fmac_f32 %1, %6, %13\n\t"                                           \
        "v_fmac_f32 %2, %7, %12\n\t"                                           \
        "v_fmac_f32 %3, %7, %13\n\t"                                           \
        : "+v"(xA0), "+v"(xA1), "+v"(xB0), "+v"(xB1),                          \
          "=&s"(sg0), "=&s"(sg1), "=&s"(sg2), "=&s"(sg3)                       \
        : "v"(c0_), "v"(c1_),                                                  \
          "v"(u0a), "v"(u1a), "v"(u0b), "v"(u1b),                              \
          "s"(lA_), "s"(lB_))

// 2 k-words, 1 extra row, 2 batches: 4 RL + 4 fmac.
#define YB2(c0_, c1_, ua, ub, lA_, lB_)                                        \
    asm("v_readlane_b32 %2, %6, %10\n\t"                                       \
        "v_readlane_b32 %3, %6, %11\n\t"                                       \
        "v_readlane_b32 %4, %7, %10\n\t"                                       \
        "v_readlane_b32 %5, %7, %11\n\t"                                       \
        "v_fmac_f32 %0, %2, %8\n\t"                                            \
        "v_fmac_f32 %1, %3, %8\n\t"                                            \
        "v_fmac_f32 %0, %4, %9\n\t"                                            \
        "v_fmac_f32 %1, %5, %9\n\t"                                            \
        : "+v"(yA), "+v"(yB),                                                  \
          "=&s"(sg0), "=&s"(sg1), "=&s"(sg2), "=&s"(sg3)                       \
        : "v"(c0_), "v"(c1_), "v"(ua), "v"(ub),                                \
          "s"(lA_), "s"(lB_))

// Extras panel, chunk-major per row, quarter chunks 6q..6q+6:
//   xwh entry (q, xr<144, cc<7) = float4 Whh1[(256+xr)*100 + (6q+cc)*4 .. +3]
//   xwi entry (q, xi<32,  cc<7) = float4 Wih1[(368+xi)*100 + (6q+cc)*4 .. +3]
__global__ void prep_kernel(const float* __restrict__ Wih1,
                            const float* __restrict__ Whh1,
                            float* __restrict__ wsT) {
    int idx = blockIdx.x * 256 + threadIdx.x;     // float index
    if (idx >= NXW4 * 4) return;
    int f = idx & 3, f4 = idx >> 2;
    float v;
    if (f4 < NXWH4) {
        int q = f4 / (144*7), r = f4 % (144*7);
        int xr = r / 7, cc = r % 7;
        v = Whh1[(256 + xr) * HH + (6*q + cc)*4 + f];
    } else {
        int r  = f4 - NXWH4;
        int q  = r / (32*7), r2 = r % (32*7);
        int xi = r2 / 7, cc = r2 % 7;
        v = Wih1[(368 + xi) * HH + (6*q + cc)*4 + f];
    }
    wsT[idx] = v;
}

// 1024 threads = 16 waves, 4 waves/SIMD (hard 128-reg cap, gfx950 unified).
// wid = t>>6; rg = wid>>2 (row-group), q = wid&3 (K-quarter; = SIMD under
// round-robin, so the one heavy row-group lands once per SIMD).
// Quarters (chunk-aligned so the RL lane base 6q is one wave-uniform SGPR):
//   q0: chunks 0-5, q1: 6-11, q2: 12-17, q3: 18-24 (7th chunk via wlq3 LDS).
// Main rows (grow = 256*rg + 4*lane + r):
//   grow<400: Whh0[grow] (h0) | <768: Wih1[grow-400] (h0) | else Whh1[grow-768] (h1)
// Extras: rg2 waves (h0): Wih1 rows 368-399, lanes 0-31, 1 row each.
//         rg3 waves (h1): Whh1 rows 256-399: pass1 rows {lane, 64+lane},
//         pass2 row {128+lane} (lane<16).
// Partials: gAll[b][q][grow], gXh[b][q][0..143], gXi[b][q][0..31]; Phase B
// sums the 4 quarters.
__global__
__attribute__((amdgpu_flat_work_group_size(1024, 1024), amdgpu_waves_per_eu(4, 4)))
void lstm_kernel(const float* __restrict__ X,     // (512,168)
                 const float* __restrict__ Wih0,  // (400,1)
                 const float* __restrict__ Whh0,  // (400,100)
                 const float* __restrict__ bih0,
                 const float* __restrict__ bhh0,
                 const float* __restrict__ Wih1,  // (400,100)
                 const float* __restrict__ Whh1,  // (400,100)
                 const float* __restrict__ bih1,
                 const float* __restrict__ bhh1,
                 const float* __restrict__ fcw,   // (100)
                 const float* __restrict__ fcb,   // (1)
                 const float* __restrict__ wsT,   // extras panel, packed
                 float* __restrict__ out)         // (512,48)
{
    __shared__ __align__(16) float shs[2][2][SHP];   // [layer][batch][k], pad zeros
    __shared__ __align__(16) float4 xw4[NXW4];       // extras panel (78.8 KB)
    __shared__ __align__(16) float4 wlq3[256][4];    // q3 main chunk 24 (16 KB)
    __shared__ __align__(16) float gAll[2][4][1024]; // [b][q][grow] partials (32 KB)
    __shared__ float gXh[2][4][144];                 // Whh1-extra partials
    __shared__ float gXi[2][4][32];                  // Wih1-extra partials
    __shared__ float sb0[G4], sb1[G4], sw0[G4], sfcw[HH];
    __shared__ float yacc[2], ybuf[2];

    const int t    = threadIdx.x;
    const int lane = t & 63;
    const int wid  = t >> 6;
    const int rg   = wid >> 2;        // row-group 0..3
    const int q    = wid & 3;         // K-quarter 0..3
    const int wg   = blockIdx.x;
    const int b0   = wg * 2;

    // ---- one-time init ----
    for (int i = t; i < 2 * 2 * SHP; i += 1024) ((float*)shs)[i] = 0.0f;
    for (int i = t; i < NXW4; i += 1024) xw4[i] = ((const float4*)wsT)[i];
    if (t < G4) {
        sb0[t] = bih0[t] + bhh0[t];
        sb1[t] = bih1[t] + bhh1[t];
        sw0[t] = Wih0[t];
    }
    if (t < HH) sfcw[t] = fcw[t];
    if (t == 0) { yacc[0] = yacc[1] = 0.0f; ybuf[0] = ybuf[1] = 0.0f; }
    const float fcb0 = fcb[0];

    // ---- main weights: 4 rows x 6 chunks = 96 floats in regs ----
    const int gbase = 256 * rg + 4 * lane;
    float wv[96];                                    // [r*24 + 4*cc + word]
    #pragma unroll
    for (int r = 0; r < 4; ++r) {
        const int g = gbase + r;
        const float* Wp = (g < 400) ? (Whh0 + g * HH)
                        : (g < 768) ? (Wih1 + (g - 400) * HH)
                                    : (Whh1 + (g - 768) * HH);
        #pragma unroll
        for (int cc = 0; cc < 6; ++cc) {
            float4 a = ((const float4*)Wp)[6 * q + cc];
            wv[r*24 + 4*cc + 0] = a.x; wv[r*24 + 4*cc + 1] = a.y;
            wv[r*24 + 4*cc + 2] = a.z; wv[r*24 + 4*cc + 3] = a.w;
        }
        if (q == 3) wlq3[rg * 64 + lane][r] = ((const float4*)Wp)[24];
    }
    #pragma unroll
    for (int j = 0; j < 96; j += 4)
        asm volatile("" : "+v"(wv[j]), "+v"(wv[j+1]), "+v"(wv[j+2]), "+v"(wv[j+3]));

    // wave-uniform h-layer (rg<3 -> h0, rg3 -> h1); extras match their wave's hv.
    const float* hbase = (rg < 3) ? &shs[0][0][0] : &shs[1][0][0];
    // wave-uniform RL lane base for this quarter (SGPR)
    const int laU = __builtin_amdgcn_readfirstlane(6 * q);
    const int qx  = rg * 64 + lane;   // wlq3 index (q3 threads)

    // cell-update params
    float c0 = 0.0f, c1 = 0.0f;
    const int ub = (t < 200) ? (t / 100) : ((t - 200) / 100);
    const int uj = (t < 200) ? (t % 100) : ((t - 200) % 100);
    const float* xrow = X + (b0 + ub) * LSEQ;

    __syncthreads();

    #pragma unroll 1
    for (int tick = 0; tick < NTICK; ++tick) {
        const bool ydtick = (tick >= 2) && ((tick - 2) % LSEQ == LSEQ - 1);
        asm volatile("" ::: "memory");   // keep per-tick LDS reads in place (no LICM)

        // ================= Phase A =================
        {
            const int li = (lane < 56) ? lane : 55;
            const float4 hv = ((const float4*)hbase)[li];   // one ds_read_b128
            float sg0, sg1, sg2, sg3;

            // ---- mains: 4 rows x quarter-K ----
            {
                float aA0=0.f,aA1=0.f,aA2=0.f,aA3=0.f,aB0=0.f,aB1=0.f,aB2=0.f,aB3=0.f;
                #pragma unroll
                for (int cc = 0; cc < 6; ++cc) {
                    const int lA = laU + cc, lB = lA + 28;
                    KB2(hv.x, hv.y,
                        wv[0*24+4*cc+0], wv[1*24+4*cc+0], wv[2*24+4*cc+0], wv[3*24+4*cc+0],
                        wv[0*24+4*cc+1], wv[1*24+4*cc+1], wv[2*24+4*cc+1], wv[3*24+4*cc+1],
                        lA, lB);
                    KB2(hv.z, hv.w,
                        wv[0*24+4*cc+2], wv[1*24+4*cc+2], wv[2*24+4*cc+2], wv[3*24+4*cc+2],
                        wv[0*24+4*cc+3], wv[1*24+4*cc+3], wv[2*24+4*cc+3], wv[3*24+4*cc+3],
                        lA, lB);
                }
                if (q == 3) {                        // chunk 24 from LDS
                    const int lA = laU + 6, lB = lA + 28;
                    const float4 e0 = wlq3[qx][0], e1 = wlq3[qx][1];
                    const float4 e2 = wlq3[qx][2], e3 = wlq3[qx][3];
                    KB2(hv.x, hv.y, e0.x,e1.x,e2.x,e3.x, e0.y,e1.y,e2.y,e3.y, lA, lB);
                    KB2(hv.z, hv.w, e0.z,e1.z,e2.z,e3.z, e0.w,e1.w,e2.w,e3.w, lA, lB);
                }
                *(float4*)&gAll[0][q][gbase] = make_float4(aA0, aA1, aA2, aA3);
                *(float4*)&gAll[1][q][gbase] = make_float4(aB0, aB1, aB2, aB3);
            }

            // ---- rg3: Whh1-extras (h1), pass 1: rows lane, 64+lane ----
            if (rg == 3) {
                {
                    float xA0=0.f, xA1=0.f, xB0=0.f, xB1=0.f;
                    const float4* xp0 = xw4 + (q * 144 + lane) * 7;
                    const float4* xp1 = xw4 + (q * 144 + 64 + lane) * 7;
                    #pragma unroll
                    for (int cc = 0; cc < 6; ++cc) {
                        const int lA = laU + cc, lB = lA + 28;
                        const float4 u0 = xp0[cc], u1 = xp1[cc];
                        XB2(hv.x, hv.y, u0.x, u1.x, u0.y, u1.y, lA, lB);
                        XB2(hv.z, hv.w, u0.z, u1.z, u0.w, u1.w, lA, lB);
                        asm volatile("" ::: "memory");
                    }
                    if (q == 3) {
                        const int lA = laU + 6, lB = lA + 28;
                        const float4 u0 = xp0[6], u1 = xp1[6];
                        XB2(hv.x, hv.y, u0.x, u1.x, u0.y, u1.y, lA, lB);
                        XB2(hv.z, hv.w, u0.z, u1.z, u0.w, u1.w, lA, lB);
                    }
                    gXh[0][q][lane]      = xA0;  gXh[1][q][lane]      = xB0;
                    gXh[0][q][64 + lane] = xA1;  gXh[1][q][64 + lane] = xB1;
                }
                {   // pass 2: row 128+lane (lane<16; others compute+discard)
                    float yA = 0.f, yB = 0.f;
                    const float4* xp2 = xw4 + (q * 144 + ((lane < 16) ? 128 + lane : lane)) * 7;
                    #pragma unroll
                    for (int cc = 0; cc < 6; ++cc) {
                        const int lA = laU + cc, lB = lA + 28;
                        const float4 u = xp2[cc];
                        YB2(hv.x, hv.y, u.x, u.y, lA, lB);
                        YB2(hv.z, hv.w, u.z, u.w, lA, lB);
                        asm volatile("" ::: "memory");
                    }
                    if (q == 3) {
                        const int lA = laU + 6, lB = lA + 28;
                        const float4 u = xp2[6];
                        YB2(hv.x, hv.y, u.x, u.y, lA, lB);
                        YB2(hv.z, hv.w, u.z, u.w, lA, lB);
                    }
                    if (lane < 16) { gXh[0][q][128 + lane] = yA; gXh[1][q][128 + lane] = yB; }
                }
            }

            // ---- rg2: Wih1-extras (h0), rows 368+lane (lane<32) ----
            if (rg == 2) {
                float yA = 0.f, yB = 0.f;
                const float4* xp = xw4 + NXWH4 + (q * 32 + ((lane < 32) ? lane : 0)) * 7;
                #pragma unroll
                for (int cc = 0; cc < 6; ++cc) {
                    const int lA = laU + cc, lB = lA + 28;
                    const float4 u = xp[cc];
                    YB2(hv.x, hv.y, u.x, u.y, lA, lB);
                    YB2(hv.z, hv.w, u.z, u.w, lA, lB);
                    asm volatile("" ::: "memory");
                }
                if (q == 3) {
                    const int lA = laU + 6, lB = lA + 28;
                    const float4 u = xp[6];
                    YB2(hv.x, hv.y, u.x, u.y, lA, lB);
                    YB2(hv.z, hv.w, u.z, u.w, lA, lB);
                }
                if (lane < 32) { gXi[0][q][lane] = yA; gXi[1][q][lane] = yB; }
            }
        }
        if (ydtick && t < 200) {
            atomicAdd(&yacc[ub], sfcw[uj] * shs[1][ub][uj]);
        }
        __syncthreads();

        // ================= Phase B =================
#define GQ4(IDX) (gAll[b][0][IDX] + gAll[b][1][IDX] + gAll[b][2][IDX] + gAll[b][3][IDX])
        if (t < 200) {
            if (tick < 8064) {               // L0, global step g0 = tick
                const int s = tick / LSEQ, p = tick % LSEQ;
                float x;
                if (s == 0)            x = xrow[p];
                else if (p < LSEQ - 1) x = xrow[p + 1];
                else                   x = ybuf[ub];
                const int j = uj, b = ub;
                float Gi = sb0[j]       + sw0[j]       * x + GQ4(j);
                float Gf = sb0[100 + j] + sw0[100 + j] * x + GQ4(100 + j);
                float Gg = sb0[200 + j] + sw0[200 + j] * x + GQ4(200 + j);
                float Go = sb0[300 + j] + sw0[300 + j] * x + GQ4(300 + j);
                c0 = sigmoidf_(Gf) * c0 + sigmoidf_(Gi) * tanhf_(Gg);
                shs[0][b][j] = sigmoidf_(Go) * tanhf_(c0);
            }
        } else if (t < 400) {
            if (tick >= 1 && tick <= 8064) { // L1, global step g1 = tick-1
                const int j = uj, b = ub;
                // Wih1 row r: r<368 -> gAll[.][400+r], else gXi[.][r-368]
                // Whh1 row r: r<256 -> gAll[.][768+r], else gXh[.][r-256]
                float Gi = sb1[j]       + GQ4(400 + j) + GQ4(768 + j);
                float Gf = sb1[100 + j] + GQ4(500 + j) + GQ4(868 + j);
                float bg = (j < 56) ? GQ4(968 + j)
                                    : (gXh[b][0][j-56] + gXh[b][1][j-56] +
                                       gXh[b][2][j-56] + gXh[b][3][j-56]);
                float Gg = sb1[200 + j] + GQ4(600 + j) + bg;
                float ao = (j < 68) ? GQ4(700 + j)
                                    : (gXi[b][0][j-68] + gXi[b][1][j-68] +
                                       gXi[b][2][j-68] + gXi[b][3][j-68]);
                float bo = gXh[b][0][44 + j] + gXh[b][1][44 + j] +
                           gXh[b][2][44 + j] + gXh[b][3][44 + j];
                float Go = sb1[300 + j] + ao + bo;
                c1 = sigmoidf_(Gf) * c1 + sigmoidf_(Gi) * tanhf_(Gg);
                shs[1][b][j] = sigmoidf_(Go) * tanhf_(c1);
            }
        } else if (t == 1023) {
            if (ydtick) {
                const int s = (tick - 2) / LSEQ;
                float y0 = yacc[0] + fcb0;
                float y1 = yacc[1] + fcb0;
                ybuf[0] = y0; ybuf[1] = y1;
                out[b0 * STEPS + s]       = y0;
                out[(b0 + 1) * STEPS + s] = y1;
                yacc[0] = 0.0f; yacc[1] = 0.0f;
            }
        }
#undef GQ4
        __syncthreads();
    }
}

extern "C" void kernel_launch(void* const* d_in, const int* in_sizes, int n_in,
                              void* d_out, int out_size, void* d_ws, size_t ws_size,
                              hipStream_t stream) {
    const float* X    = (const float*)d_in[0];
    const float* Wih0 = (const float*)d_in[1];
    const float* Whh0 = (const float*)d_in[2];
    const float* bih0 = (const float*)d_in[3];
    const float* bhh0 = (const float*)d_in[4];
    const float* Wih1 = (const float*)d_in[5];
    const float* Whh1 = (const float*)d_in[6];
    const float* bih1 = (const float*)d_in[7];
    const float* bhh1 = (const float*)d_in[8];
    const float* fcw  = (const float*)d_in[9];
    const float* fcb  = (const float*)d_in[10];
    float* out = (float*)d_out;
    float* wsT = (float*)d_ws;   // 4928 float4 = 78,848 B

    hipLaunchKernelGGL(prep_kernel, dim3((NXW4 * 4 + 255) / 256), dim3(256), 0, stream,
                       Wih1, Whh1, wsT);
    hipLaunchKernelGGL(lstm_kernel, dim3(256), dim3(1024), 0, stream,
                       X, Wih0, Whh0, bih0, bhh0, Wih1, Whh1, bih1, bhh1,
                       fcw, fcb, wsT, out);
}

// Round 10
// 36786.365 us; speedup vs baseline: 1.5223x; 1.5223x over previous
//
#include <hip/hip_runtime.h>

#define HH    100
#define G4    400
#define LSEQ  168
#define STEPS 48
#define NTICK 8066     // L0 at tick t (t<8064), L1 at tick t-1
#define SHP   112      // padded h stride (zeros beyond 100)
#define NX    176      // extra rows: Wih1 368..399 (32) + Whh1 256..399 (144)
#define NX4   4400     // float4 units in the extra-row panel
#define NX4P  4416     // padded (waves 13..15 read up to idx 4415)

__device__ __forceinline__ float sigmoidf_(float x) {
    return 1.0f / (1.0f + __expf(-x));
}
__device__ __forceinline__ float tanhf_(float x) {
    return 1.0f - 2.0f / (__expf(2.0f * x) + 1.0f);
}

// ---- DPP broadcast-FMA blocks --------------------------------------------
// Round-6 lesson: v_readlane costs ~7cy VALU issue -> 800 RL/SIMD/tick was
// the bottleneck. DPP row_newbcast:n broadcasts lane n within each 16-lane
// row as a FREE src0 modifier on v_fmac_f32 (2cy issue, no extra instr).
// h is loaded replicated per 16-lane row (lane l holds chunk l&15), so one
// fused DPP-fmac replaces readlane+fmac. Blocks chain through "+v"
// accumulators -> indivisible, no operand clustering (rounds 1-4 cascade).
// Round-9 lesson: list-macros (HA8/WV4) need a variadic indirection layer,
// since macro-arg COUNTING happens before argument expansion.

#define DCH(...)   DCH_I(__VA_ARGS__)
#define DCH0(...)  DCH0_I(__VA_ARGS__)
#define DCHX(...)  DCHX_I(__VA_ARGS__)
#define DCHX0(...) DCHX0_I(__VA_ARGS__)

// One 4-k chunk, 2 batches: 8 DPP-fmacs. N_ = broadcast lane (0..15).
#define DCH_I(N_, ax,ay,az,aw, bx,by,bz,bw, w0_,w1_,w2_,w3_)                   \
    asm("v_fmac_f32_dpp %0, %2, %10 row_newbcast:" #N_ " row_mask:0xf bank_mask:0xf\n\t" \
        "v_fmac_f32_dpp %1, %6, %10 row_newbcast:" #N_ " row_mask:0xf bank_mask:0xf\n\t" \
        "v_fmac_f32_dpp %0, %3, %11 row_newbcast:" #N_ " row_mask:0xf bank_mask:0xf\n\t" \
        "v_fmac_f32_dpp %1, %7, %11 row_newbcast:" #N_ " row_mask:0xf bank_mask:0xf\n\t" \
        "v_fmac_f32_dpp %0, %4, %12 row_newbcast:" #N_ " row_mask:0xf bank_mask:0xf\n\t" \
        "v_fmac_f32_dpp %1, %8, %12 row_newbcast:" #N_ " row_mask:0xf bank_mask:0xf\n\t" \
        "v_fmac_f32_dpp %0, %5, %13 row_newbcast:" #N_ " row_mask:0xf bank_mask:0xf\n\t" \
        "v_fmac_f32_dpp %1, %9, %13 row_newbcast:" #N_ " row_mask:0xf bank_mask:0xf\n\t" \
        : "+v"(a0), "+v"(a1)                                                   \
        : "v"(ax), "v"(ay), "v"(az), "v"(aw),                                  \
          "v"(bx), "v"(by), "v"(bz), "v"(bw),                                  \
          "v"(w0_), "v"(w1_), "v"(w2_), "v"(w3_))

// First block variant: leading s_nop guards the (load->DPP-read) window.
#define DCH0_I(N_, ax,ay,az,aw, bx,by,bz,bw, w0_,w1_,w2_,w3_)                  \
    asm("s_nop 1\n\t"                                                          \
        "v_fmac_f32_dpp %0, %2, %10 row_newbcast:" #N_ " row_mask:0xf bank_mask:0xf\n\t" \
        "v_fmac_f32_dpp %1, %6, %10 row_newbcast:" #N_ " row_mask:0xf bank_mask:0xf\n\t" \
        "v_fmac_f32_dpp %0, %3, %11 row_newbcast:" #N_ " row_mask:0xf bank_mask:0xf\n\t" \
        "v_fmac_f32_dpp %1, %7, %11 row_newbcast:" #N_ " row_mask:0xf bank_mask:0xf\n\t" \
        "v_fmac_f32_dpp %0, %4, %12 row_newbcast:" #N_ " row_mask:0xf bank_mask:0xf\n\t" \
        "v_fmac_f32_dpp %1, %8, %12 row_newbcast:" #N_ " row_mask:0xf bank_mask:0xf\n\t" \
        "v_fmac_f32_dpp %0, %5, %13 row_newbcast:" #N_ " row_mask:0xf bank_mask:0xf\n\t" \
        "v_fmac_f32_dpp %1, %9, %13 row_newbcast:" #N_ " row_mask:0xf bank_mask:0xf\n\t" \
        : "+v"(a0), "+v"(a1)                                                   \
        : "v"(ax), "v"(ay), "v"(az), "v"(aw),                                  \
          "v"(bx), "v"(by), "v"(bz), "v"(bw),                                  \
          "v"(w0_), "v"(w1_), "v"(w2_), "v"(w3_))

// Heavy-wave variant: + extra-row stream (xa0/xa1 vs w4). 16 DPP-fmacs,
// each accumulator chain spaced 4 instrs (8cy) -> FMA latency covered.
#define DCHX_I(N_, ax,ay,az,aw, bx,by,bz,bw, w0_,w1_,w2_,w3_, x0_,x1_,x2_,x3_) \
    asm("v_fmac_f32_dpp %0, %4, %12 row_newbcast:" #N_ " row_mask:0xf bank_mask:0xf\n\t" \
        "v_fmac_f32_dpp %1, %8, %12 row_newbcast:" #N_ " row_mask:0xf bank_mask:0xf\n\t" \
        "v_fmac_f32_dpp %2, %4, %16 row_newbcast:" #N_ " row_mask:0xf bank_mask:0xf\n\t" \
        "v_fmac_f32_dpp %3, %8, %16 row_newbcast:" #N_ " row_mask:0xf bank_mask:0xf\n\t" \
        "v_fmac_f32_dpp %0, %5, %13 row_newbcast:" #N_ " row_mask:0xf bank_mask:0xf\n\t" \
        "v_fmac_f32_dpp %1, %9, %13 row_newbcast:" #N_ " row_mask:0xf bank_mask:0xf\n\t" \
        "v_fmac_f32_dpp %2, %5, %17 row_newbcast:" #N_ " row_mask:0xf bank_mask:0xf\n\t" \
        "v_fmac_f32_dpp %3, %9, %17 row_newbcast:" #N_ " row_mask:0xf bank_mask:0xf\n\t" \
        "v_fmac_f32_dpp %0, %6, %14 row_newbcast:" #N_ " row_mask:0xf bank_mask:0xf\n\t" \
        "v_fmac_f32_dpp %1, %10, %14 row_newbcast:" #N_ " row_mask:0xf bank_mask:0xf\n\t" \
        "v_fmac_f32_dpp %2, %6, %18 row_newbcast:" #N_ " row_mask:0xf bank_mask:0xf\n\t" \
        "v_fmac_f32_dpp %3, %10, %18 row_newbcast:" #N_ " row_mask:0xf bank_mask:0xf\n\t" \
        "v_fmac_f32_dpp %0, %7, %15 row_newbcast:" #N_ " row_mask:0xf bank_mask:0xf\n\t" \
        "v_fmac_f32_dpp %1, %11, %15 row_newbcast:" #N_ " row_mask:0xf bank_mask:0xf\n\t" \
        "v_fmac_f32_dpp %2, %7, %19 row_newbcast:" #N_ " row_mask:0xf bank_mask:0xf\n\t" \
        "v_fmac_f32_dpp %3, %11, %19 row_newbcast:" #N_ " row_mask:0xf bank_mask:0xf\n\t" \
        : "+v"(a0), "+v"(a1), "+v"(xa0), "+v"(xa1)                             \
        : "v"(ax), "v"(ay), "v"(az), "v"(aw),                                  \
          "v"(bx), "v"(by), "v"(bz), "v"(bw),                                  \
          "v"(w0_), "v"(w1_), "v"(w2_), "v"(w3_),                              \
          "v"(x0_), "v"(x1_), "v"(x2_), "v"(x3_))

#define DCHX0_I(N_, ax,ay,az,aw, bx,by,bz,bw, w0_,w1_,w2_,w3_, x0_,x1_,x2_,x3_)\
    asm("s_nop 1\n\t"                                                          \
        "v_fmac_f32_dpp %0, %4, %12 row_newbcast:" #N_ " row_mask:0xf bank_mask:0xf\n\t" \
        "v_fmac_f32_dpp %1, %8, %12 row_newbcast:" #N_ " row_mask:0xf bank_mask:0xf\n\t" \
        "v_fmac_f32_dpp %2, %4, %16 row_newbcast:" #N_ " row_mask:0xf bank_mask:0xf\n\t" \
        "v_fmac_f32_dpp %3, %8, %16 row_newbcast:" #N_ " row_mask:0xf bank_mask:0xf\n\t" \
        "v_fmac_f32_dpp %0, %5, %13 row_newbcast:" #N_ " row_mask:0xf bank_mask:0xf\n\t" \
        "v_fmac_f32_dpp %1, %9, %13 row_newbcast:" #N_ " row_mask:0xf bank_mask:0xf\n\t" \
        "v_fmac_f32_dpp %2, %5, %17 row_newbcast:" #N_ " row_mask:0xf bank_mask:0xf\n\t" \
        "v_fmac_f32_dpp %3, %9, %17 row_newbcast:" #N_ " row_mask:0xf bank_mask:0xf\n\t" \
        "v_fmac_f32_dpp %0, %6, %14 row_newbcast:" #N_ " row_mask:0xf bank_mask:0xf\n\t" \
        "v_fmac_f32_dpp %1, %10, %14 row_newbcast:" #N_ " row_mask:0xf bank_mask:0xf\n\t" \
        "v_fmac_f32_dpp %2, %6, %18 row_newbcast:" #N_ " row_mask:0xf bank_mask:0xf\n\t" \
        "v_fmac_f32_dpp %3, %10, %18 row_newbcast:" #N_ " row_mask:0xf bank_mask:0xf\n\t" \
        "v_fmac_f32_dpp %0, %7, %15 row_newbcast:" #N_ " row_mask:0xf bank_mask:0xf\n\t" \
        "v_fmac_f32_dpp %1, %11, %15 row_newbcast:" #N_ " row_mask:0xf bank_mask:0xf\n\t" \
        "v_fmac_f32_dpp %2, %7, %19 row_newbcast:" #N_ " row_mask:0xf bank_mask:0xf\n\t" \
        "v_fmac_f32_dpp %3, %11, %19 row_newbcast:" #N_ " row_mask:0xf bank_mask:0xf\n\t" \
        : "+v"(a0), "+v"(a1), "+v"(xa0), "+v"(xa1)                             \
        : "v"(ax), "v"(ay), "v"(az), "v"(aw),                                  \
          "v"(bx), "v"(by), "v"(bz), "v"(bw),                                  \
          "v"(w0_), "v"(w1_), "v"(w2_), "v"(w3_),                              \
          "v"(x0_), "v"(x1_), "v"(x2_), "v"(x3_))

#define HA8 hA0.x,hA0.y,hA0.z,hA0.w, hB0.x,hB0.y,hB0.z,hB0.w
#define HB8 hA1.x,hA1.y,hA1.z,hA1.w, hB1.x,hB1.y,hB1.z,hB1.w
#define WV4(C_) wv[4*(C_)], wv[4*(C_)+1], wv[4*(C_)+2], wv[4*(C_)+3]

// Extra-row weights packed transposed for coalesced dwordx4 access.
// float4 units:
//   group 0 (wave 4, B-extras):  idx4 = c*32 + l           row = 368+l (l<32), src Wih1
//   group g=1..3 (waves 13..15): idx4 = 800 + (g-1)*1200 + c*48 + l
//                                row = 256 + (g-1)*48 + l (l<48), src Whh1
// c = 0..24 chunks of 4 (covers k=0..99 exactly). Total 4400 float4 = 70,400 B.
__global__ void prep_kernel(const float* __restrict__ Wih1,
                            const float* __restrict__ Whh1,
                            float* __restrict__ wsT) {
    int idx = blockIdx.x * 256 + threadIdx.x;     // float index
    if (idx >= NX4 * 4) return;
    int f = idx & 3, q4 = idx >> 2;
    float v;
    if (q4 < 800) {
        int c = q4 / 32, l = q4 % 32;
        v = Wih1[(368 + l) * HH + c * 4 + f];
    } else {
        int r = q4 - 800, grp = r / 1200, rr = r % 1200;
        int c = rr / 48, l = rr % 48;
        v = Whh1[(256 + grp * 48 + l) * HH + c * 4 + f];
    }
    wsT[idx] = v;
}

// 1024 threads = 16 waves = 4 waves/SIMD (hard 128-reg cap, gfx950 unified).
// Wave-aligned unit map (thread t owns one K=100 row-unit):
//   t <  400 : Whh0 row t        (input h0)  -> L0 gate partial, gAll[b][t]
//   t <  768 : Wih1 row t-400    (input h0)  -> L1 "a" partial,  gAll[b][400+r]
//   t < 1024 : Whh1 row t-768    (input h1)  -> L1 "b" partial,  gAll[b][768+r]
// Extra rows staged in LDS (xlds), one heavy wave per SIMD:
//   wave  4 : Wih1 rows 368..399 (h0) -> gX[b][144+l]
//   wave 13 : Whh1 rows 256..303 (h1) -> gX[b][l]
//   wave 14 : Whh1 rows 304..351 (h1) -> gX[b][48+l]
//   wave 15 : Whh1 rows 352..399 (h1) -> gX[b][96+l]
// h distribution: lane l holds h-chunk (l&15) — replicated per 16-lane row —
// in 4 b128 regs (chunks 0-15 and 16-24, batches A,B); each k-step is one
// fused v_fmac_f32_dpp row_newbcast (no readlane, no per-lane broadcast LDS).
__global__
__attribute__((amdgpu_flat_work_group_size(1024, 1024), amdgpu_waves_per_eu(4, 4)))
void lstm_kernel(const float* __restrict__ X,     // (512,168)
                 const float* __restrict__ Wih0,  // (400,1)
                 const float* __restrict__ Whh0,  // (400,100)
                 const float* __restrict__ bih0,
                 const float* __restrict__ bhh0,
                 const float* __restrict__ Wih1,  // (400,100)
                 const float* __restrict__ Whh1,  // (400,100)
                 const float* __restrict__ bih1,
                 const float* __restrict__ bhh1,
                 const float* __restrict__ fcw,   // (100)
                 const float* __restrict__ fcb,   // (1)
                 const float* __restrict__ wsT,   // extra rows, packed
                 float* __restrict__ out)         // (512,48)
{
    __shared__ __align__(16) float shs[2][2][SHP];   // [layer][batch][k], pad zeros
    __shared__ __align__(16) float4 wlds[2][1024];   // weight chunks 23,24 per unit
    __shared__ __align__(16) float4 xlds[NX4P];      // extra-row panel (70.6 KB)
    __shared__ float gAll[2][1024];                  // per-batch unit partials
    __shared__ float gX[2][NX];                      // extra-row full-dot partials
    __shared__ float sb0[G4], sb1[G4], sw0[G4], sfcw[HH];
    __shared__ float yacc[2], ybuf[2];

    const int t    = threadIdx.x;
    const int lane = t & 63;
    const int wid  = t >> 6;
    const int wg   = blockIdx.x;
    const int b0   = wg * 2;

    // ---- one-time init ----
    for (int i = t; i < 2 * 2 * SHP; i += 1024) ((float*)shs)[i] = 0.0f;
    for (int i = t; i < NX4P; i += 1024)
        xlds[i] = (i < NX4) ? ((const float4*)wsT)[i] : make_float4(0.f, 0.f, 0.f, 0.f);
    if (t < G4) {
        sb0[t] = bih0[t] + bhh0[t];
        sb1[t] = bih1[t] + bhh1[t];
        sw0[t] = Wih0[t];
    }
    if (t < HH) sfcw[t] = fcw[t];
    if (t == 0) { yacc[0] = yacc[1] = 0.0f; ybuf[0] = ybuf[1] = 0.0f; }
    const float fcb0 = fcb[0];

    // ---- register-resident weights: 92 floats (23 float4 chunks) ----
    // Round-0/6-proven pin: allocator splits arch/acc itself.
    const float* wrow = (t < 400) ? (Whh0 + t * HH)
                      : (t < 768) ? (Wih1 + (t - 400) * HH)
                                  : (Whh1 + (t - 768) * HH);
    float wv[92];
    #pragma unroll
    for (int j = 0; j < 23; ++j) {
        float4 a = ((const float4*)wrow)[j];
        wv[4*j] = a.x; wv[4*j+1] = a.y; wv[4*j+2] = a.z; wv[4*j+3] = a.w;
    }
    #pragma unroll
    for (int j = 0; j < 92; j += 4)
        asm volatile("" : "+v"(wv[j]), "+v"(wv[j+1]), "+v"(wv[j+2]), "+v"(wv[j+3]));
    // chunks 23,24 live in LDS
    wlds[0][t] = ((const float4*)wrow)[23];
    wlds[1][t] = ((const float4*)wrow)[24];

    // wave-uniform input layer for the main FMA (h0 for waves 0..11, h1 for 12..15)
    const float* hbase = (t < 768) ? &shs[0][0][0] : &shs[1][0][0];

    // h-chunk indices for the replicated DPP layout
    const int r16 = lane & 15;
    const int cL  = r16;                          // chunks 0..15
    const int cH  = 16 + ((r16 < 9) ? r16 : 8);   // chunks 16..24 (clamped)

    // extra-row stream config (wave-uniform)
    const bool xtr   = (wid == 4) || (wid >= 13);
    const int  nact  = (wid == 4) ? 32 : 48;
    const int  xbase = (wid == 4) ? 0 : 800 + (wid - 13) * 1200;
    const int  xu0   = (wid == 4) ? 144 : (wid - 13) * 48;
    const float4* xw = xlds + xbase + lane;          // + c*nact per chunk (LDS)

    // cell-update params
    float c0 = 0.0f, c1 = 0.0f;
    const int ub = (t < 200) ? (t / 100) : ((t - 200) / 100);
    const int uj = (t < 200) ? (t % 100) : ((t - 200) % 100);
    const float* xrow = X + (b0 + ub) * LSEQ;

    __syncthreads();

    #pragma unroll 1
    for (int tick = 0; tick < NTICK; ++tick) {
        const bool ydtick = (tick >= 2) && ((tick - 2) % LSEQ == LSEQ - 1);

        // ================= Phase A: all FMA work =================
        {
            // replicated h: lane l holds chunk (l&15) / 16+(l&15) for A and B
            const float4 hA0 = *(const float4*)(hbase + 4 * cL);
            const float4 hA1 = *(const float4*)(hbase + 4 * cH);
            const float4 hB0 = *(const float4*)(hbase + SHP + 4 * cL);
            const float4 hB1 = *(const float4*)(hbase + SHP + 4 * cH);
            float a0 = 0.f, a1 = 0.f, xa0 = 0.f, xa1 = 0.f;

            if (!xtr) {
                DCH0(0,  HA8, WV4(0));
                DCH(1,  HA8, WV4(1));   DCH(2,  HA8, WV4(2));
                DCH(3,  HA8, WV4(3));   DCH(4,  HA8, WV4(4));
                DCH(5,  HA8, WV4(5));   DCH(6,  HA8, WV4(6));
                DCH(7,  HA8, WV4(7));   DCH(8,  HA8, WV4(8));
                DCH(9,  HA8, WV4(9));   DCH(10, HA8, WV4(10));
                DCH(11, HA8, WV4(11));  DCH(12, HA8, WV4(12));
                DCH(13, HA8, WV4(13));  DCH(14, HA8, WV4(14));
                DCH(15, HA8, WV4(15));
                DCH(0,  HB8, WV4(16));  DCH(1,  HB8, WV4(17));
                DCH(2,  HB8, WV4(18));  DCH(3,  HB8, WV4(19));
                DCH(4,  HB8, WV4(20));  DCH(5,  HB8, WV4(21));
                DCH(6,  HB8, WV4(22));
                { const float4 wl = wlds[0][t]; DCH(7, HB8, wl.x, wl.y, wl.z, wl.w); }
                { const float4 wl = wlds[1][t]; DCH(8, HB8, wl.x, wl.y, wl.z, wl.w); }
            } else {
                { const float4 w4 = xw[0*nact];  DCHX0(0,  HA8, WV4(0),  w4.x,w4.y,w4.z,w4.w); }
                { const float4 w4 = xw[1*nact];  DCHX(1,  HA8, WV4(1),  w4.x,w4.y,w4.z,w4.w); }
                { const float4 w4 = xw[2*nact];  DCHX(2,  HA8, WV4(2),  w4.x,w4.y,w4.z,w4.w); }
                { const float4 w4 = xw[3*nact];  DCHX(3,  HA8, WV4(3),  w4.x,w4.y,w4.z,w4.w); }
                { const float4 w4 = xw[4*nact];  DCHX(4,  HA8, WV4(4),  w4.x,w4.y,w4.z,w4.w); }
                { const float4 w4 = xw[5*nact];  DCHX(5,  HA8, WV4(5),  w4.x,w4.y,w4.z,w4.w); }
                { const float4 w4 = xw[6*nact];  DCHX(6,  HA8, WV4(6),  w4.x,w4.y,w4.z,w4.w); }
                { const float4 w4 = xw[7*nact];  DCHX(7,  HA8, WV4(7),  w4.x,w4.y,w4.z,w4.w); }
                { const float4 w4 = xw[8*nact];  DCHX(8,  HA8, WV4(8),  w4.x,w4.y,w4.z,w4.w); }
                { const float4 w4 = xw[9*nact];  DCHX(9,  HA8, WV4(9),  w4.x,w4.y,w4.z,w4.w); }
                { const float4 w4 = xw[10*nact]; DCHX(10, HA8, WV4(10), w4.x,w4.y,w4.z,w4.w); }
                { const float4 w4 = xw[11*nact]; DCHX(11, HA8, WV4(11), w4.x,w4.y,w4.z,w4.w); }
                { const float4 w4 = xw[12*nact]; DCHX(12, HA8, WV4(12), w4.x,w4.y,w4.z,w4.w); }
                { const float4 w4 = xw[13*nact]; DCHX(13, HA8, WV4(13), w4.x,w4.y,w4.z,w4.w); }
                { const float4 w4 = xw[14*nact]; DCHX(14, HA8, WV4(14), w4.x,w4.y,w4.z,w4.w); }
                { const float4 w4 = xw[15*nact]; DCHX(15, HA8, WV4(15), w4.x,w4.y,w4.z,w4.w); }
                { const float4 w4 = xw[16*nact]; DCHX(0,  HB8, WV4(16), w4.x,w4.y,w4.z,w4.w); }
                { const float4 w4 = xw[17*nact]; DCHX(1,  HB8, WV4(17), w4.x,w4.y,w4.z,w4.w); }
                { const float4 w4 = xw[18*nact]; DCHX(2,  HB8, WV4(18), w4.x,w4.y,w4.z,w4.w); }
                { const float4 w4 = xw[19*nact]; DCHX(3,  HB8, WV4(19), w4.x,w4.y,w4.z,w4.w); }
                { const float4 w4 = xw[20*nact]; DCHX(4,  HB8, WV4(20), w4.x,w4.y,w4.z,w4.w); }
                { const float4 w4 = xw[21*nact]; DCHX(5,  HB8, WV4(21), w4.x,w4.y,w4.z,w4.w); }
                { const float4 w4 = xw[22*nact]; DCHX(6,  HB8, WV4(22), w4.x,w4.y,w4.z,w4.w); }
                { const float4 w4 = xw[23*nact]; const float4 wl = wlds[0][t];
                  DCHX(7, HB8, wl.x, wl.y, wl.z, wl.w, w4.x, w4.y, w4.z, w4.w); }
                { const float4 w4 = xw[24*nact]; const float4 wl = wlds[1][t];
                  DCHX(8, HB8, wl.x, wl.y, wl.z, wl.w, w4.x, w4.y, w4.z, w4.w); }
            }

            gAll[0][t] = a0; gAll[1][t] = a1;
            if (xtr && lane < nact) { gX[0][xu0 + lane] = xa0; gX[1][xu0 + lane] = xa1; }
        }
        if (ydtick && t < 200) {
            atomicAdd(&yacc[ub], sfcw[uj] * shs[1][ub][uj]);
        }
        __syncthreads();

        // ================= Phase B: cell updates =================
        if (t < 200) {
            if (tick < 8064) {               // L0, global step g0 = tick
                const int s = tick / LSEQ, p = tick % LSEQ;
                float x;
                if (s == 0)            x = xrow[p];
                else if (p < LSEQ - 1) x = xrow[p + 1];
                else                   x = ybuf[ub];
                const int j = uj, b = ub;
                float Gi = sb0[j]       + sw0[j]       * x + gAll[b][j];
                float Gf = sb0[100 + j] + sw0[100 + j] * x + gAll[b][100 + j];
                float Gg = sb0[200 + j] + sw0[200 + j] * x + gAll[b][200 + j];
                float Go = sb0[300 + j] + sw0[300 + j] * x + gAll[b][300 + j];
                c0 = sigmoidf_(Gf) * c0 + sigmoidf_(Gi) * tanhf_(Gg);
                shs[0][b][j] = sigmoidf_(Go) * tanhf_(c0);
            }
        } else if (t < 400) {
            if (tick >= 1 && tick <= 8064) { // L1, global step g1 = tick-1
                const int j = uj, b = ub;
                // Wih1 row r: r<368 -> gAll[b][400+r], else gX[b][144+(r-368)]
                // Whh1 row r: r<256 -> gAll[b][768+r], else gX[b][r-256]
                float Gi = sb1[j]       + gAll[b][400 + j] + gAll[b][768 + j];
                float Gf = sb1[100 + j] + gAll[b][500 + j] + gAll[b][868 + j];
                float Gg = sb1[200 + j] + gAll[b][600 + j]
                         + ((j < 56) ? gAll[b][968 + j] : gX[b][j - 56]);
                float Go = sb1[300 + j]
                         + ((j < 68) ? gAll[b][700 + j] : gX[b][144 + j - 68])
                         + gX[b][44 + j];
                c1 = sigmoidf_(Gf) * c1 + sigmoidf_(Gi) * tanhf_(Gg);
                shs[1][b][j] = sigmoidf_(Go) * tanhf_(c1);
            }
        } else if (t == 1023) {
            if (ydtick) {
                const int s = (tick - 2) / LSEQ;
                float y0 = yacc[0] + fcb0;
                float y1 = yacc[1] + fcb0;
                ybuf[0] = y0; ybuf[1] = y1;
                out[b0 * STEPS + s]       = y0;
                out[(b0 + 1) * STEPS + s] = y1;
                yacc[0] = 0.0f; yacc[1] = 0.0f;
            }
        }
        __syncthreads();
    }
}

extern "C" void kernel_launch(void* const* d_in, const int* in_sizes, int n_in,
                              void* d_out, int out_size, void* d_ws, size_t ws_size,
                              hipStream_t stream) {
    const float* X    = (const float*)d_in[0];
    const float* Wih0 = (const float*)d_in[1];
    const float* Whh0 = (const float*)d_in[2];
    const float* bih0 = (const float*)d_in[3];
    const float* bhh0 = (const float*)d_in[4];
    const float* Wih1 = (const float*)d_in[5];
    const float* Whh1 = (const float*)d_in[6];
    const float* bih1 = (const float*)d_in[7];
    const float* bhh1 = (const float*)d_in[8];
    const float* fcw  = (const float*)d_in[9];
    const float* fcb  = (const float*)d_in[10];
    float* out = (float*)d_out;
    float* wsT = (float*)d_ws;   // 4400 float4 = 70,400 B

    hipLaunchKernelGGL(prep_kernel, dim3((NX4 * 4 + 255) / 256), dim3(256), 0, stream,
                       Wih1, Whh1, wsT);
    hipLaunchKernelGGL(lstm_kernel, dim3(256), dim3(1024), 0, stream,
                       X, Wih0, Whh0, bih0, bhh0, Wih1, Whh1, bih1, bhh1,
                       fcw, fcb, wsT, out);
}

// Round 11
// 30828.592 us; speedup vs baseline: 1.8164x; 1.1933x over previous
//
#include <hip/hip_runtime.h>

#define HH    100
#define G4    400
#define LSEQ  168
#define STEPS 48
#define NTICK 8066     // per-batch ticks: L0 at tick t (t<8064), L1 at tick t-1
#define SHP   112      // padded h stride (zeros beyond 100)
#define NX    176      // extra rows: Wih1 368..399 (32) + Whh1 256..399 (144)
#define NX4   4400     // float4 units in the extra-row panel
#define NX4P  4416     // padded (waves 13..15 read up to idx 4415)

__device__ __forceinline__ float sigmoidf_(float x) {
    return 1.0f / (1.0f + __expf(-x));
}
__device__ __forceinline__ float tanhf_(float x) {
    return 1.0f - 2.0f / (__expf(2.0f * x) + 1.0f);
}

// ---- DPP broadcast-FMA blocks (single-batch) ------------------------------
// Round-10 lesson: v_fmac_f32_dpp issues at ~4.4cy (half fmac rate) but beats
// readlane (7cy) and LDS broadcast (12cy/b128 port). Kept. This round: each
// window computes ONE batch's dots, so blocks are 4 fmacs (2 accumulator
// chains, distance 2 = 8cy >= latency). Variadic indirection layer per
// round-9 lesson (macro-arg counting precedes expansion).

#define DC1(...)   DC1_I(__VA_ARGS__)
#define DC10(...)  DC10_I(__VA_ARGS__)
#define DC1X(...)  DC1X_I(__VA_ARGS__)
#define DC1X0(...) DC1X0_I(__VA_ARGS__)

// One 4-k chunk, 1 batch: 4 DPP-fmacs, chains a0/a0b.
#define DC1_I(N_, hx,hy,hz,hw, w0_,w1_,w2_,w3_)                                \
    asm("v_fmac_f32_dpp %0, %2, %6 row_newbcast:" #N_ " row_mask:0xf bank_mask:0xf\n\t" \
        "v_fmac_f32_dpp %1, %3, %7 row_newbcast:" #N_ " row_mask:0xf bank_mask:0xf\n\t" \
        "v_fmac_f32_dpp %0, %4, %8 row_newbcast:" #N_ " row_mask:0xf bank_mask:0xf\n\t" \
        "v_fmac_f32_dpp %1, %5, %9 row_newbcast:" #N_ " row_mask:0xf bank_mask:0xf\n\t" \
        : "+v"(a0), "+v"(a0b)                                                  \
        : "v"(hx), "v"(hy), "v"(hz), "v"(hw),                                  \
          "v"(w0_), "v"(w1_), "v"(w2_), "v"(w3_))

// First block after the h load: s_nop guards the load->DPP-read window.
#define DC10_I(N_, hx,hy,hz,hw, w0_,w1_,w2_,w3_)                               \
    asm("s_nop 1\n\t"                                                          \
        "v_fmac_f32_dpp %0, %2, %6 row_newbcast:" #N_ " row_mask:0xf bank_mask:0xf\n\t" \
        "v_fmac_f32_dpp %1, %3, %7 row_newbcast:" #N_ " row_mask:0xf bank_mask:0xf\n\t" \
        "v_fmac_f32_dpp %0, %4, %8 row_newbcast:" #N_ " row_mask:0xf bank_mask:0xf\n\t" \
        "v_fmac_f32_dpp %1, %5, %9 row_newbcast:" #N_ " row_mask:0xf bank_mask:0xf\n\t" \
        : "+v"(a0), "+v"(a0b)                                                  \
        : "v"(hx), "v"(hy), "v"(hz), "v"(hw),                                  \
          "v"(w0_), "v"(w1_), "v"(w2_), "v"(w3_))

// Heavy-wave variant: + extras stream. 8 fmacs, 4 chains, distance 4.
#define DC1X_I(N_, hx,hy,hz,hw, w0_,w1_,w2_,w3_, x0_,x1_,x2_,x3_)              \
    asm("v_fmac_f32_dpp %0, %4, %8 row_newbcast:" #N_ " row_mask:0xf bank_mask:0xf\n\t"  \
        "v_fmac_f32_dpp %2, %4, %12 row_newbcast:" #N_ " row_mask:0xf bank_mask:0xf\n\t" \
        "v_fmac_f32_dpp %1, %5, %9 row_newbcast:" #N_ " row_mask:0xf bank_mask:0xf\n\t"  \
        "v_fmac_f32_dpp %3, %5, %13 row_newbcast:" #N_ " row_mask:0xf bank_mask:0xf\n\t" \
        "v_fmac_f32_dpp %0, %6, %10 row_newbcast:" #N_ " row_mask:0xf bank_mask:0xf\n\t" \
        "v_fmac_f32_dpp %2, %6, %14 row_newbcast:" #N_ " row_mask:0xf bank_mask:0xf\n\t" \
        "v_fmac_f32_dpp %1, %7, %11 row_newbcast:" #N_ " row_mask:0xf bank_mask:0xf\n\t" \
        "v_fmac_f32_dpp %3, %7, %15 row_newbcast:" #N_ " row_mask:0xf bank_mask:0xf\n\t" \
        : "+v"(a0), "+v"(a0b), "+v"(xa0), "+v"(xa0b)                           \
        : "v"(hx), "v"(hy), "v"(hz), "v"(hw),                                  \
          "v"(w0_), "v"(w1_), "v"(w2_), "v"(w3_),                              \
          "v"(x0_), "v"(x1_), "v"(x2_), "v"(x3_))

#define DC1X0_I(N_, hx,hy,hz,hw, w0_,w1_,w2_,w3_, x0_,x1_,x2_,x3_)             \
    asm("s_nop 1\n\t"                                                          \
        "v_fmac_f32_dpp %0, %4, %8 row_newbcast:" #N_ " row_mask:0xf bank_mask:0xf\n\t"  \
        "v_fmac_f32_dpp %2, %4, %12 row_newbcast:" #N_ " row_mask:0xf bank_mask:0xf\n\t" \
        "v_fmac_f32_dpp %1, %5, %9 row_newbcast:" #N_ " row_mask:0xf bank_mask:0xf\n\t"  \
        "v_fmac_f32_dpp %3, %5, %13 row_newbcast:" #N_ " row_mask:0xf bank_mask:0xf\n\t" \
        "v_fmac_f32_dpp %0, %6, %10 row_newbcast:" #N_ " row_mask:0xf bank_mask:0xf\n\t" \
        "v_fmac_f32_dpp %2, %6, %14 row_newbcast:" #N_ " row_mask:0xf bank_mask:0xf\n\t" \
        "v_fmac_f32_dpp %1, %7, %11 row_newbcast:" #N_ " row_mask:0xf bank_mask:0xf\n\t" \
        "v_fmac_f32_dpp %3, %7, %15 row_newbcast:" #N_ " row_mask:0xf bank_mask:0xf\n\t" \
        : "+v"(a0), "+v"(a0b), "+v"(xa0), "+v"(xa0b)                           \
        : "v"(hx), "v"(hy), "v"(hz), "v"(hw),                                  \
          "v"(w0_), "v"(w1_), "v"(w2_), "v"(w3_),                              \
          "v"(x0_), "v"(x1_), "v"(x2_), "v"(x3_))

#define H0A hA0.x,hA0.y,hA0.z,hA0.w
#define H1A hA1.x,hA1.y,hA1.z,hA1.w
#define WV4(C_) wv[4*(C_)], wv[4*(C_)+1], wv[4*(C_)+2], wv[4*(C_)+3]

// Extras panel (unchanged from round 10; verified):
//   group 0 (wave 4):  idx4 = c*32 + l   row = 368+l (l<32), src Wih1
//   group g=1..3 (waves 13..15): idx4 = 800 + (g-1)*1200 + c*48 + l
//                                row = 256 + (g-1)*48 + l (l<48), src Whh1
__global__ void prep_kernel(const float* __restrict__ Wih1,
                            const float* __restrict__ Whh1,
                            float* __restrict__ wsT) {
    int idx = blockIdx.x * 256 + threadIdx.x;     // float index
    if (idx >= NX4 * 4) return;
    int f = idx & 3, q4 = idx >> 2;
    float v;
    if (q4 < 800) {
        int c = q4 / 32, l = q4 % 32;
        v = Wih1[(368 + l) * HH + c * 4 + f];
    } else {
        int r = q4 - 800, grp = r / 1200, rr = r % 1200;
        int c = rr / 48, l = rr % 48;
        v = Whh1[(256 + grp * 48 + l) * HH + c * 4 + f];
    }
    wsT[idx] = v;
}

// Batch-staggered schedule: window w (0..2*NTICK), ONE barrier per window.
//   bx = w&1  : Phase-A batch, tick tA = w>>1  (dots -> gAll[bx], gX[bx])
//   ob = bx^1 : Phase-B batch, tick tB = (w-1)>>1 (cell updates, w>=1)
// Phase-B tasks live on threads 512..711 (waves 8..11 — one per SIMD), each
// thread permanently owns (layer, j) with c-state in regs cA/cB per batch.
// Dataflow: gAll/gX[b] written in w, read in w+1 (cross-barrier); shs[.][bx]
// read while shs[.][ob] written (disjoint); y atomics in bx's Phase-A window,
// finalize by t=1023 next window, ybuf consumed 166 ticks later.
__global__
__attribute__((amdgpu_flat_work_group_size(1024, 1024), amdgpu_waves_per_eu(4, 4)))
void lstm_kernel(const float* __restrict__ X,     // (512,168)
                 const float* __restrict__ Wih0,  // (400,1)
                 const float* __restrict__ Whh0,  // (400,100)
                 const float* __restrict__ bih0,
                 const float* __restrict__ bhh0,
                 const float* __restrict__ Wih1,  // (400,100)
                 const float* __restrict__ Whh1,  // (400,100)
                 const float* __restrict__ bih1,
                 const float* __restrict__ bhh1,
                 const float* __restrict__ fcw,   // (100)
                 const float* __restrict__ fcb,   // (1)
                 const float* __restrict__ wsT,   // extra rows, packed
                 float* __restrict__ out)         // (512,48)
{
    __shared__ __align__(16) float shs[2][2][SHP];   // [layer][batch][k], pad zeros
    __shared__ __align__(16) float4 wlds[2][1024];   // weight chunks 23,24 per unit
    __shared__ __align__(16) float4 xlds[NX4P];      // extra-row panel (70.6 KB)
    __shared__ float gAll[2][1024];                  // [batch][unit] partials
    __shared__ float gX[2][NX];                      // [batch] extra-row dots
    __shared__ float sb0[G4], sb1[G4], sw0[G4], sfcw[HH];
    __shared__ float yacc[2], ybuf[2];

    const int t    = threadIdx.x;
    const int lane = t & 63;
    const int wid  = t >> 6;
    const int wg   = blockIdx.x;
    const int b0   = wg * 2;

    // ---- one-time init ----
    for (int i = t; i < 2 * 2 * SHP; i += 1024) ((float*)shs)[i] = 0.0f;
    for (int i = t; i < NX4P; i += 1024)
        xlds[i] = (i < NX4) ? ((const float4*)wsT)[i] : make_float4(0.f, 0.f, 0.f, 0.f);
    if (t < G4) {
        sb0[t] = bih0[t] + bhh0[t];
        sb1[t] = bih1[t] + bhh1[t];
        sw0[t] = Wih0[t];
    }
    if (t < HH) sfcw[t] = fcw[t];
    if (t == 0) { yacc[0] = yacc[1] = 0.0f; ybuf[0] = ybuf[1] = 0.0f; }
    const float fcb0 = fcb[0];

    // ---- register-resident weights: 92 floats (23 float4 chunks) ----
    const float* wrow = (t < 400) ? (Whh0 + t * HH)
                      : (t < 768) ? (Wih1 + (t - 400) * HH)
                                  : (Whh1 + (t - 768) * HH);
    float wv[92];
    #pragma unroll
    for (int j = 0; j < 23; ++j) {
        float4 a = ((const float4*)wrow)[j];
        wv[4*j] = a.x; wv[4*j+1] = a.y; wv[4*j+2] = a.z; wv[4*j+3] = a.w;
    }
    #pragma unroll
    for (int j = 0; j < 92; j += 4)
        asm volatile("" : "+v"(wv[j]), "+v"(wv[j+1]), "+v"(wv[j+2]), "+v"(wv[j+3]));
    // chunks 23,24 live in LDS
    wlds[0][t] = ((const float4*)wrow)[23];
    wlds[1][t] = ((const float4*)wrow)[24];

    // wave-uniform input layer (h0 for waves 0..11, h1 for 12..15)
    const float* hbase = (t < 768) ? &shs[0][0][0] : &shs[1][0][0];

    // h-chunk indices for the replicated DPP layout
    const int r16 = lane & 15;
    const int cL  = r16;                          // chunks 0..15
    const int cH  = 16 + ((r16 < 9) ? r16 : 8);   // chunks 16..24 (clamped)

    // extra-row stream config (wave-uniform)
    const bool xtr   = (wid == 4) || (wid >= 13);
    const int  nact  = (wid == 4) ? 32 : 48;
    const int  xbase = (wid == 4) ? 0 : 800 + (wid - 13) * 1200;
    const int  xu0   = (wid == 4) ? 144 : (wid - 13) * 48;
    const float4* xw = xlds + xbase + lane;          // + c*nact per chunk (LDS)

    // Phase-B task (threads 512..711): task=(t-512); layer=task/100, j=task%100
    const bool pbth = (t >= 512 && t < 712);
    const int  task = t - 512;
    const int  pj   = (task < 100) ? task : task - 100;
    float cA = 0.0f, cB = 0.0f;                      // cell state, batch 0/1
    const float* xrA = X + b0 * LSEQ;
    const float* xrB = X + (b0 + 1) * LSEQ;

    __syncthreads();

    #pragma unroll 1
    for (int w = 0; w <= 2 * NTICK; ++w) {
        const int bx = w & 1;           // Phase-A batch
        const int tA = w >> 1;
        const int ob = bx ^ 1;          // Phase-B batch
        const int tB = (w - 1) >> 1;
        const bool doA = (tA < NTICK);

        // ---- finalize y for previous window's Phase-A batch ----
        if (t == 1023 && w >= 1) {
            const int pbx = (w - 1) & 1, ptA = (w - 1) >> 1;
            if (ptA >= 2 && (ptA - 2) % LSEQ == LSEQ - 1) {
                const int s = (ptA - 2) / LSEQ;
                float y = yacc[pbx] + fcb0;
                ybuf[pbx] = y;
                out[(b0 + pbx) * STEPS + s] = y;
                yacc[pbx] = 0.0f;
            }
        }

        // ================= Phase A: dots for batch bx =================
        if (doA) {
            const float* hsel = hbase + bx * SHP;
            const float4 hA0 = *(const float4*)(hsel + 4 * cL);
            const float4 hA1 = *(const float4*)(hsel + 4 * cH);
            float a0 = 0.f, a0b = 0.f, xa0 = 0.f, xa0b = 0.f;

            if (!xtr) {
                DC10(0,  H0A, WV4(0));
                DC1(1,  H0A, WV4(1));   DC1(2,  H0A, WV4(2));
                DC1(3,  H0A, WV4(3));   DC1(4,  H0A, WV4(4));
                DC1(5,  H0A, WV4(5));   DC1(6,  H0A, WV4(6));
                DC1(7,  H0A, WV4(7));   DC1(8,  H0A, WV4(8));
                DC1(9,  H0A, WV4(9));   DC1(10, H0A, WV4(10));
                DC1(11, H0A, WV4(11));  DC1(12, H0A, WV4(12));
                DC1(13, H0A, WV4(13));  DC1(14, H0A, WV4(14));
                DC1(15, H0A, WV4(15));
                DC1(0,  H1A, WV4(16));  DC1(1,  H1A, WV4(17));
                DC1(2,  H1A, WV4(18));  DC1(3,  H1A, WV4(19));
                DC1(4,  H1A, WV4(20));  DC1(5,  H1A, WV4(21));
                DC1(6,  H1A, WV4(22));
                { const float4 wl = wlds[0][t]; DC1(7, H1A, wl.x, wl.y, wl.z, wl.w); }
                { const float4 wl = wlds[1][t]; DC1(8, H1A, wl.x, wl.y, wl.z, wl.w); }
            } else {
                { const float4 x4 = xw[0*nact];  DC1X0(0,  H0A, WV4(0),  x4.x,x4.y,x4.z,x4.w); }
                { const float4 x4 = xw[1*nact];  DC1X(1,  H0A, WV4(1),  x4.x,x4.y,x4.z,x4.w); }
                { const float4 x4 = xw[2*nact];  DC1X(2,  H0A, WV4(2),  x4.x,x4.y,x4.z,x4.w); }
                { const float4 x4 = xw[3*nact];  DC1X(3,  H0A, WV4(3),  x4.x,x4.y,x4.z,x4.w); }
                { const float4 x4 = xw[4*nact];  DC1X(4,  H0A, WV4(4),  x4.x,x4.y,x4.z,x4.w); }
                { const float4 x4 = xw[5*nact];  DC1X(5,  H0A, WV4(5),  x4.x,x4.y,x4.z,x4.w); }
                { const float4 x4 = xw[6*nact];  DC1X(6,  H0A, WV4(6),  x4.x,x4.y,x4.z,x4.w); }
                { const float4 x4 = xw[7*nact];  DC1X(7,  H0A, WV4(7),  x4.x,x4.y,x4.z,x4.w); }
                { const float4 x4 = xw[8*nact];  DC1X(8,  H0A, WV4(8),  x4.x,x4.y,x4.z,x4.w); }
                { const float4 x4 = xw[9*nact];  DC1X(9,  H0A, WV4(9),  x4.x,x4.y,x4.z,x4.w); }
                { const float4 x4 = xw[10*nact]; DC1X(10, H0A, WV4(10), x4.x,x4.y,x4.z,x4.w); }
                { const float4 x4 = xw[11*nact]; DC1X(11, H0A, WV4(11), x4.x,x4.y,x4.z,x4.w); }
                { const float4 x4 = xw[12*nact]; DC1X(12, H0A, WV4(12), x4.x,x4.y,x4.z,x4.w); }
                { const float4 x4 = xw[13*nact]; DC1X(13, H0A, WV4(13), x4.x,x4.y,x4.z,x4.w); }
                { const float4 x4 = xw[14*nact]; DC1X(14, H0A, WV4(14), x4.x,x4.y,x4.z,x4.w); }
                { const float4 x4 = xw[15*nact]; DC1X(15, H0A, WV4(15), x4.x,x4.y,x4.z,x4.w); }
                { const float4 x4 = xw[16*nact]; DC1X(0,  H1A, WV4(16), x4.x,x4.y,x4.z,x4.w); }
                { const float4 x4 = xw[17*nact]; DC1X(1,  H1A, WV4(17), x4.x,x4.y,x4.z,x4.w); }
                { const float4 x4 = xw[18*nact]; DC1X(2,  H1A, WV4(18), x4.x,x4.y,x4.z,x4.w); }
                { const float4 x4 = xw[19*nact]; DC1X(3,  H1A, WV4(19), x4.x,x4.y,x4.z,x4.w); }
                { const float4 x4 = xw[20*nact]; DC1X(4,  H1A, WV4(20), x4.x,x4.y,x4.z,x4.w); }
                { const float4 x4 = xw[21*nact]; DC1X(5,  H1A, WV4(21), x4.x,x4.y,x4.z,x4.w); }
                { const float4 x4 = xw[22*nact]; DC1X(6,  H1A, WV4(22), x4.x,x4.y,x4.z,x4.w); }
                { const float4 x4 = xw[23*nact]; const float4 wl = wlds[0][t];
                  DC1X(7, H1A, wl.x, wl.y, wl.z, wl.w, x4.x, x4.y, x4.z, x4.w); }
                { const float4 x4 = xw[24*nact]; const float4 wl = wlds[1][t];
                  DC1X(8, H1A, wl.x, wl.y, wl.z, wl.w, x4.x, x4.y, x4.z, x4.w); }
            }

            gAll[bx][t] = a0 + a0b;
            if (xtr && lane < nact) gX[bx][xu0 + lane] = xa0 + xa0b;

            // y-dot atomics for batch bx (reads shs[1][bx], stable this window)
            if (tA >= 2 && (tA - 2) % LSEQ == LSEQ - 1 && t < 100) {
                atomicAdd(&yacc[bx], sfcw[t] * shs[1][bx][t]);
            }
        }

        // ================= Phase B: cell updates for batch ob =================
        if (w >= 1 && pbth) {
            const int j = pj, b = ob;
            if (task < 100) {                    // L0, global step g0 = tB
                if (tB < 8064) {
                    const int s = tB / LSEQ, p = tB % LSEQ;
                    const float* xr = (b == 0) ? xrA : xrB;
                    float x;
                    if (s == 0)            x = xr[p];
                    else if (p < LSEQ - 1) x = xr[p + 1];
                    else                   x = ybuf[b];
                    float Gi = sb0[j]       + sw0[j]       * x + gAll[b][j];
                    float Gf = sb0[100 + j] + sw0[100 + j] * x + gAll[b][100 + j];
                    float Gg = sb0[200 + j] + sw0[200 + j] * x + gAll[b][200 + j];
                    float Go = sb0[300 + j] + sw0[300 + j] * x + gAll[b][300 + j];
                    float cc = (b == 0) ? cA : cB;
                    cc = sigmoidf_(Gf) * cc + sigmoidf_(Gi) * tanhf_(Gg);
                    shs[0][b][j] = sigmoidf_(Go) * tanhf_(cc);
                    if (b == 0) cA = cc; else cB = cc;
                }
            } else {                             // L1, global step g1 = tB-1
                if (tB >= 1 && tB <= 8064) {
                    // Wih1 row r: r<368 -> gAll[b][400+r], else gX[b][144+(r-368)]
                    // Whh1 row r: r<256 -> gAll[b][768+r], else gX[b][r-256]
                    float Gi = sb1[j]       + gAll[b][400 + j] + gAll[b][768 + j];
                    float Gf = sb1[100 + j] + gAll[b][500 + j] + gAll[b][868 + j];
                    float Gg = sb1[200 + j] + gAll[b][600 + j]
                             + ((j < 56) ? gAll[b][968 + j] : gX[b][j - 56]);
                    float Go = sb1[300 + j]
                             + ((j < 68) ? gAll[b][700 + j] : gX[b][144 + j - 68])
                             + gX[b][44 + j];
                    float cc = (b == 0) ? cA : cB;
                    cc = sigmoidf_(Gf) * cc + sigmoidf_(Gi) * tanhf_(Gg);
                    shs[1][b][j] = sigmoidf_(Go) * tanhf_(cc);
                    if (b == 0) cA = cc; else cB = cc;
                }
            }
        }

        __syncthreads();
    }
}

extern "C" void kernel_launch(void* const* d_in, const int* in_sizes, int n_in,
                              void* d_out, int out_size, void* d_ws, size_t ws_size,
                              hipStream_t stream) {
    const float* X    = (const float*)d_in[0];
    const float* Wih0 = (const float*)d_in[1];
    const float* Whh0 = (const float*)d_in[2];
    const float* bih0 = (const float*)d_in[3];
    const float* bhh0 = (const float*)d_in[4];
    const float* Wih1 = (const float*)d_in[5];
    const float* Whh1 = (const float*)d_in[6];
    const float* bih1 = (const float*)d_in[7];
    const float* bhh1 = (const float*)d_in[8];
    const float* fcw  = (const float*)d_in[9];
    const float* fcb  = (const float*)d_in[10];
    float* out = (float*)d_out;
    float* wsT = (float*)d_ws;   // 4400 float4 = 70,400 B

    hipLaunchKernelGGL(prep_kernel, dim3((NX4 * 4 + 255) / 256), dim3(256), 0, stream,
                       Wih1, Whh1, wsT);
    hipLaunchKernelGGL(lstm_kernel, dim3(256), dim3(1024), 0, stream,
                       X, Wih0, Whh0, bih0, bhh0, Wih1, Whh1, bih1, bhh1,
                       fcw, fcb, wsT, out);
}

// Round 13
// 30782.010 us; speedup vs baseline: 1.8192x; 1.0015x over previous
//
#include <hip/hip_runtime.h>

#define HH    100
#define G4    400
#define LSEQ  168
#define STEPS 48
#define NTICK 8066     // per-batch ticks: L0 at tick t (t<8064), L1 at tick t-1
#define SHP   112      // padded h stride (zeros beyond 100)
#define NX    176      // extra rows: Wih1 368..399 (32) + Whh1 256..399 (144)
#define NX4   4400     // float4 units in the extra-row panel
#define NX4P  4416     // padded (waves 13..15 read up to idx 4415)

__device__ __forceinline__ float sigmoidf_(float x) {
    return 1.0f / (1.0f + __expf(-x));
}
__device__ __forceinline__ float tanhf_(float x) {
    return 1.0f - 2.0f / (__expf(2.0f * x) + 1.0f);
}

// ---- DPP broadcast-FMA blocks (single-batch) ------------------------------
// v_fmac_f32_dpp row_newbcast: broadcast within 16-lane rows fused into the
// fmac (~4.4cy issue; beats readlane 7cy and LDS-broadcast). Variadic
// indirection layer per round-9 lesson. Blocks chain through "+v"
// accumulators -> indivisible (rounds 1-4 spill cascade prevention).

#define DC1(...)   DC1_I(__VA_ARGS__)
#define DC10(...)  DC10_I(__VA_ARGS__)
#define DC1X(...)  DC1X_I(__VA_ARGS__)
#define DC1X0(...) DC1X0_I(__VA_ARGS__)

// One 4-k chunk, 1 batch: 4 DPP-fmacs, chains a0/a0b.
#define DC1_I(N_, hx,hy,hz,hw, w0_,w1_,w2_,w3_)                                \
    asm("v_fmac_f32_dpp %0, %2, %6 row_newbcast:" #N_ " row_mask:0xf bank_mask:0xf\n\t" \
        "v_fmac_f32_dpp %1, %3, %7 row_newbcast:" #N_ " row_mask:0xf bank_mask:0xf\n\t" \
        "v_fmac_f32_dpp %0, %4, %8 row_newbcast:" #N_ " row_mask:0xf bank_mask:0xf\n\t" \
        "v_fmac_f32_dpp %1, %5, %9 row_newbcast:" #N_ " row_mask:0xf bank_mask:0xf\n\t" \
        : "+v"(a0), "+v"(a0b)                                                  \
        : "v"(hx), "v"(hy), "v"(hz), "v"(hw),                                  \
          "v"(w0_), "v"(w1_), "v"(w2_), "v"(w3_))

// First block after the h load: s_nop guards the load->DPP-read window.
#define DC10_I(N_, hx,hy,hz,hw, w0_,w1_,w2_,w3_)                               \
    asm("s_nop 1\n\t"                                                          \
        "v_fmac_f32_dpp %0, %2, %6 row_newbcast:" #N_ " row_mask:0xf bank_mask:0xf\n\t" \
        "v_fmac_f32_dpp %1, %3, %7 row_newbcast:" #N_ " row_mask:0xf bank_mask:0xf\n\t" \
        "v_fmac_f32_dpp %0, %4, %8 row_newbcast:" #N_ " row_mask:0xf bank_mask:0xf\n\t" \
        "v_fmac_f32_dpp %1, %5, %9 row_newbcast:" #N_ " row_mask:0xf bank_mask:0xf\n\t" \
        : "+v"(a0), "+v"(a0b)                                                  \
        : "v"(hx), "v"(hy), "v"(hz), "v"(hw),                                  \
          "v"(w0_), "v"(w1_), "v"(w2_), "v"(w3_))

// Heavy-wave variant: + extras stream. 8 fmacs, 4 chains, distance 4.
#define DC1X_I(N_, hx,hy,hz,hw, w0_,w1_,w2_,w3_, x0_,x1_,x2_,x3_)              \
    asm("v_fmac_f32_dpp %0, %4, %8 row_newbcast:" #N_ " row_mask:0xf bank_mask:0xf\n\t"  \
        "v_fmac_f32_dpp %2, %4, %12 row_newbcast:" #N_ " row_mask:0xf bank_mask:0xf\n\t" \
        "v_fmac_f32_dpp %1, %5, %9 row_newbcast:" #N_ " row_mask:0xf bank_mask:0xf\n\t"  \
        "v_fmac_f32_dpp %3, %5, %13 row_newbcast:" #N_ " row_mask:0xf bank_mask:0xf\n\t" \
        "v_fmac_f32_dpp %0, %6, %10 row_newbcast:" #N_ " row_mask:0xf bank_mask:0xf\n\t" \
        "v_fmac_f32_dpp %2, %6, %14 row_newbcast:" #N_ " row_mask:0xf bank_mask:0xf\n\t" \
        "v_fmac_f32_dpp %1, %7, %11 row_newbcast:" #N_ " row_mask:0xf bank_mask:0xf\n\t" \
        "v_fmac_f32_dpp %3, %7, %15 row_newbcast:" #N_ " row_mask:0xf bank_mask:0xf\n\t" \
        : "+v"(a0), "+v"(a0b), "+v"(xa0), "+v"(xa0b)                           \
        : "v"(hx), "v"(hy), "v"(hz), "v"(hw),                                  \
          "v"(w0_), "v"(w1_), "v"(w2_), "v"(w3_),                              \
          "v"(x0_), "v"(x1_), "v"(x2_), "v"(x3_))

#define DC1X0_I(N_, hx,hy,hz,hw, w0_,w1_,w2_,w3_, x0_,x1_,x2_,x3_)             \
    asm("s_nop 1\n\t"                                                          \
        "v_fmac_f32_dpp %0, %4, %8 row_newbcast:" #N_ " row_mask:0xf bank_mask:0xf\n\t"  \
        "v_fmac_f32_dpp %2, %4, %12 row_newbcast:" #N_ " row_mask:0xf bank_mask:0xf\n\t" \
        "v_fmac_f32_dpp %1, %5, %9 row_newbcast:" #N_ " row_mask:0xf bank_mask:0xf\n\t"  \
        "v_fmac_f32_dpp %3, %5, %13 row_newbcast:" #N_ " row_mask:0xf bank_mask:0xf\n\t" \
        "v_fmac_f32_dpp %0, %6, %10 row_newbcast:" #N_ " row_mask:0xf bank_mask:0xf\n\t" \
        "v_fmac_f32_dpp %2, %6, %14 row_newbcast:" #N_ " row_mask:0xf bank_mask:0xf\n\t" \
        "v_fmac_f32_dpp %1, %7, %11 row_newbcast:" #N_ " row_mask:0xf bank_mask:0xf\n\t" \
        "v_fmac_f32_dpp %3, %7, %15 row_newbcast:" #N_ " row_mask:0xf bank_mask:0xf\n\t" \
        : "+v"(a0), "+v"(a0b), "+v"(xa0), "+v"(xa0b)                           \
        : "v"(hx), "v"(hy), "v"(hz), "v"(hw),                                  \
          "v"(w0_), "v"(w1_), "v"(w2_), "v"(w3_),                              \
          "v"(x0_), "v"(x1_), "v"(x2_), "v"(x3_))

#define H0A hA0.x,hA0.y,hA0.z,hA0.w
#define H1A hA1.x,hA1.y,hA1.z,hA1.w
#define WV4(C_) wv[4*(C_)], wv[4*(C_)+1], wv[4*(C_)+2], wv[4*(C_)+3]

// Extras panel (verified):
//   group 0 (wave 4):  idx4 = c*32 + l   row = 368+l (l<32), src Wih1
//   group g=1..3 (waves 13..15): idx4 = 800 + (g-1)*1200 + c*48 + l
//                                row = 256 + (g-1)*48 + l (l<48), src Whh1
__global__ void prep_kernel(const float* __restrict__ Wih1,
                            const float* __restrict__ Whh1,
                            float* __restrict__ wsT) {
    int idx = blockIdx.x * 256 + threadIdx.x;     // float index
    if (idx >= NX4 * 4) return;
    int f = idx & 3, q4 = idx >> 2;
    float v;
    if (q4 < 800) {
        int c = q4 / 32, l = q4 % 32;
        v = Wih1[(368 + l) * HH + c * 4 + f];
    } else {
        int r = q4 - 800, grp = r / 1200, rr = r % 1200;
        int c = rr / 48, l = rr % 48;
        v = Whh1[(256 + grp * 48 + l) * HH + c * 4 + f];
    }
    wsT[idx] = v;
}

// Batch-staggered schedule: window w (0..2*NTICK), ONE barrier per window.
//   bx = w&1  : Phase-A batch, tick tA = w>>1  (dots -> gAll[bx], gX[bx])
//   ob = bx^1 : Phase-B batch, tick tB = (w-1)>>1 (cell updates, w>=1)
// Phase B runs BEFORE Phase A inside the window: its inputs (gAll/gX[ob]
// from window w-1) are ready at the barrier; running it first overlaps the
// serial sigmoid/tanh chain with the other waves' DPP-fmac issue, and the
// B-wave's tail becomes its own throughput-bound A-dots. Dataflow: B writes
// shs[.][ob], A reads shs[.][bx], disjoint; ybuf write (tick≡1 mod 168) vs
// read (tick≡167 mod 168) never share a window; yacc parities disjoint.
__global__
__attribute__((amdgpu_flat_work_group_size(1024, 1024), amdgpu_waves_per_eu(4, 4)))
void lstm_kernel(const float* __restrict__ X,     // (512,168)
                 const float* __restrict__ Wih0,  // (400,1)
                 const float* __restrict__ Whh0,  // (400,100)
                 const float* __restrict__ bih0,
                 const float* __restrict__ bhh0,
                 const float* __restrict__ Wih1,  // (400,100)
                 const float* __restrict__ Whh1,  // (400,100)
                 const float* __restrict__ bih1,
                 const float* __restrict__ bhh1,
                 const float* __restrict__ fcw,   // (100)
                 const float* __restrict__ fcb,   // (1)
                 const float* __restrict__ wsT,   // extra rows, packed
                 float* __restrict__ out)         // (512,48)
{
    __shared__ __align__(16) float shs[2][2][SHP];   // [layer][batch][k], pad zeros
    __shared__ __align__(16) float4 wlds[2][1024];   // weight chunks 23,24 per unit
    __shared__ __align__(16) float4 xlds[NX4P];      // extra-row panel (70.6 KB)
    __shared__ float gAll[2][1024];                  // [batch][unit] partials
    __shared__ float gX[2][NX];                      // [batch] extra-row dots
    __shared__ float sb0[G4], sb1[G4], sw0[G4], sfcw[HH];
    __shared__ float yacc[2], ybuf[2];

    const int t    = threadIdx.x;
    const int lane = t & 63;
    const int wid  = t >> 6;
    const int wg   = blockIdx.x;
    const int b0   = wg * 2;

    // ---- one-time init ----
    for (int i = t; i < 2 * 2 * SHP; i += 1024) ((float*)shs)[i] = 0.0f;
    for (int i = t; i < NX4P; i += 1024)
        xlds[i] = (i < NX4) ? ((const float4*)wsT)[i] : make_float4(0.f, 0.f, 0.f, 0.f);
    if (t < G4) {
        sb0[t] = bih0[t] + bhh0[t];
        sb1[t] = bih1[t] + bhh1[t];
        sw0[t] = Wih0[t];
    }
    if (t < HH) sfcw[t] = fcw[t];
    if (t == 0) { yacc[0] = yacc[1] = 0.0f; ybuf[0] = ybuf[1] = 0.0f; }
    const float fcb0 = fcb[0];

    // ---- register-resident weights: 92 floats (23 float4 chunks) ----
    const float* wrow = (t < 400) ? (Whh0 + t * HH)
                      : (t < 768) ? (Wih1 + (t - 400) * HH)
                                  : (Whh1 + (t - 768) * HH);
    float wv[92];
    #pragma unroll
    for (int j = 0; j < 23; ++j) {
        float4 a = ((const float4*)wrow)[j];
        wv[4*j] = a.x; wv[4*j+1] = a.y; wv[4*j+2] = a.z; wv[4*j+3] = a.w;
    }
    #pragma unroll
    for (int j = 0; j < 92; j += 4)
        asm volatile("" : "+v"(wv[j]), "+v"(wv[j+1]), "+v"(wv[j+2]), "+v"(wv[j+3]));
    // chunks 23,24 live in LDS
    wlds[0][t] = ((const float4*)wrow)[23];
    wlds[1][t] = ((const float4*)wrow)[24];

    // wave-uniform input layer (h0 for waves 0..11, h1 for 12..15)
    const float* hbase = (t < 768) ? &shs[0][0][0] : &shs[1][0][0];

    // h-chunk indices for the replicated DPP layout
    const int r16 = lane & 15;
    const int cL  = r16;                          // chunks 0..15
    const int cH  = 16 + ((r16 < 9) ? r16 : 8);   // chunks 16..24 (clamped)

    // extra-row stream config (wave-uniform)
    const bool xtr   = (wid == 4) || (wid >= 13);
    const int  nact  = (wid == 4) ? 32 : 48;
    const int  xbase = (wid == 4) ? 0 : 800 + (wid - 13) * 1200;
    const int  xu0   = (wid == 4) ? 144 : (wid - 13) * 48;
    const float4* xw = xlds + xbase + lane;          // + c*nact per chunk (LDS)

    // Phase-B task (threads 512..711): task=(t-512); layer=task/100, j=task%100
    const bool pbth = (t >= 512 && t < 712);
    const int  task = t - 512;
    const int  pj   = (task < 100) ? task : task - 100;
    float cA = 0.0f, cB = 0.0f;                      // cell state, batch 0/1
    const float* xrA = X + b0 * LSEQ;
    const float* xrB = X + (b0 + 1) * LSEQ;

    __syncthreads();

    #pragma unroll 1
    for (int w = 0; w <= 2 * NTICK; ++w) {
        const int bx = w & 1;           // Phase-A batch
        const int tA = w >> 1;
        const int ob = bx ^ 1;          // Phase-B batch
        const int tB = (w - 1) >> 1;
        const bool doA = (tA < NTICK);

        // ---- finalize y for previous window's Phase-A batch ----
        if (t == 1023 && w >= 1) {
            const int pbx = (w - 1) & 1, ptA = (w - 1) >> 1;
            if (ptA >= 2 && (ptA - 2) % LSEQ == LSEQ - 1) {
                const int s = (ptA - 2) / LSEQ;
                float y = yacc[pbx] + fcb0;
                ybuf[pbx] = y;
                out[(b0 + pbx) * STEPS + s] = y;
                yacc[pbx] = 0.0f;
            }
        }

        // ===== Phase B FIRST: cell updates for batch ob (inputs ready) =====
        if (w >= 1 && pbth) {
            const int j = pj, b = ob;
            if (task < 100) {                    // L0, global step g0 = tB
                if (tB < 8064) {
                    const int s = tB / LSEQ, p = tB % LSEQ;
                    const float* xr = (b == 0) ? xrA : xrB;
                    float x;
                    if (s == 0)            x = xr[p];
                    else if (p < LSEQ - 1) x = xr[p + 1];
                    else                   x = ybuf[b];
                    float Gi = sb0[j]       + sw0[j]       * x + gAll[b][j];
                    float Gf = sb0[100 + j] + sw0[100 + j] * x + gAll[b][100 + j];
                    float Gg = sb0[200 + j] + sw0[200 + j] * x + gAll[b][200 + j];
                    float Go = sb0[300 + j] + sw0[300 + j] * x + gAll[b][300 + j];
                    float cc = (b == 0) ? cA : cB;
                    cc = sigmoidf_(Gf) * cc + sigmoidf_(Gi) * tanhf_(Gg);
                    shs[0][b][j] = sigmoidf_(Go) * tanhf_(cc);
                    if (b == 0) cA = cc; else cB = cc;
                }
            } else {                             // L1, global step g1 = tB-1
                if (tB >= 1 && tB <= 8064) {
                    // Wih1 row r: r<368 -> gAll[b][400+r], else gX[b][144+(r-368)]
                    // Whh1 row r: r<256 -> gAll[b][768+r], else gX[b][r-256]
                    float Gi = sb1[j]       + gAll[b][400 + j] + gAll[b][768 + j];
                    float Gf = sb1[100 + j] + gAll[b][500 + j] + gAll[b][868 + j];
                    float Gg = sb1[200 + j] + gAll[b][600 + j]
                             + ((j < 56) ? gAll[b][968 + j] : gX[b][j - 56]);
                    float Go = sb1[300 + j]
                             + ((j < 68) ? gAll[b][700 + j] : gX[b][144 + j - 68])
                             + gX[b][44 + j];
                    float cc = (b == 0) ? cA : cB;
                    cc = sigmoidf_(Gf) * cc + sigmoidf_(Gi) * tanhf_(Gg);
                    shs[1][b][j] = sigmoidf_(Go) * tanhf_(cc);
                    if (b == 0) cA = cc; else cB = cc;
                }
            }
        }

        // ================= Phase A: dots for batch bx =================
        if (doA) {
            const float* hsel = hbase + bx * SHP;
            const float4 hA0 = *(const float4*)(hsel + 4 * cL);
            const float4 hA1 = *(const float4*)(hsel + 4 * cH);
            float a0 = 0.f, a0b = 0.f, xa0 = 0.f, xa0b = 0.f;

            if (!xtr) {
                DC10(0,  H0A, WV4(0));
                DC1(1,  H0A, WV4(1));   DC1(2,  H0A, WV4(2));
                DC1(3,  H0A, WV4(3));   DC1(4,  H0A, WV4(4));
                DC1(5,  H0A, WV4(5));   DC1(6,  H0A, WV4(6));
                DC1(7,  H0A, WV4(7));   DC1(8,  H0A, WV4(8));
                DC1(9,  H0A, WV4(9));   DC1(10, H0A, WV4(10));
                DC1(11, H0A, WV4(11));  DC1(12, H0A, WV4(12));
                DC1(13, H0A, WV4(13));  DC1(14, H0A, WV4(14));
                DC1(15, H0A, WV4(15));
                DC1(0,  H1A, WV4(16));  DC1(1,  H1A, WV4(17));
                DC1(2,  H1A, WV4(18));  DC1(3,  H1A, WV4(19));
                DC1(4,  H1A, WV4(20));  DC1(5,  H1A, WV4(21));
                DC1(6,  H1A, WV4(22));
                { const float4 wl = wlds[0][t]; DC1(7, H1A, wl.x, wl.y, wl.z, wl.w); }
                { const float4 wl = wlds[1][t]; DC1(8, H1A, wl.x, wl.y, wl.z, wl.w); }
            } else {
                { const float4 x4 = xw[0*nact];  DC1X0(0,  H0A, WV4(0),  x4.x,x4.y,x4.z,x4.w); }
                { const float4 x4 = xw[1*nact];  DC1X(1,  H0A, WV4(1),  x4.x,x4.y,x4.z,x4.w); }
                { const float4 x4 = xw[2*nact];  DC1X(2,  H0A, WV4(2),  x4.x,x4.y,x4.z,x4.w); }
                { const float4 x4 = xw[3*nact];  DC1X(3,  H0A, WV4(3),  x4.x,x4.y,x4.z,x4.w); }
                { const float4 x4 = xw[4*nact];  DC1X(4,  H0A, WV4(4),  x4.x,x4.y,x4.z,x4.w); }
                { const float4 x4 = xw[5*nact];  DC1X(5,  H0A, WV4(5),  x4.x,x4.y,x4.z,x4.w); }
                { const float4 x4 = xw[6*nact];  DC1X(6,  H0A, WV4(6),  x4.x,x4.y,x4.z,x4.w); }
                { const float4 x4 = xw[7*nact];  DC1X(7,  H0A, WV4(7),  x4.x,x4.y,x4.z,x4.w); }
                { const float4 x4 = xw[8*nact];  DC1X(8,  H0A, WV4(8),  x4.x,x4.y,x4.z,x4.w); }
                { const float4 x4 = xw[9*nact];  DC1X(9,  H0A, WV4(9),  x4.x,x4.y,x4.z,x4.w); }
                { const float4 x4 = xw[10*nact]; DC1X(10, H0A, WV4(10), x4.x,x4.y,x4.z,x4.w); }
                { const float4 x4 = xw[11*nact]; DC1X(11, H0A, WV4(11), x4.x,x4.y,x4.z,x4.w); }
                { const float4 x4 = xw[12*nact]; DC1X(12, H0A, WV4(12), x4.x,x4.y,x4.z,x4.w); }
                { const float4 x4 = xw[13*nact]; DC1X(13, H0A, WV4(13), x4.x,x4.y,x4.z,x4.w); }
                { const float4 x4 = xw[14*nact]; DC1X(14, H0A, WV4(14), x4.x,x4.y,x4.z,x4.w); }
                { const float4 x4 = xw[15*nact]; DC1X(15, H0A, WV4(15), x4.x,x4.y,x4.z,x4.w); }
                { const float4 x4 = xw[16*nact]; DC1X(0,  H1A, WV4(16), x4.x,x4.y,x4.z,x4.w); }
                { const float4 x4 = xw[17*nact]; DC1X(1,  H1A, WV4(17), x4.x,x4.y,x4.z,x4.w); }
                { const float4 x4 = xw[18*nact]; DC1X(2,  H1A, WV4(18), x4.x,x4.y,x4.z,x4.w); }
                { const float4 x4 = xw[19*nact]; DC1X(3,  H1A, WV4(19), x4.x,x4.y,x4.z,x4.w); }
                { const float4 x4 = xw[20*nact]; DC1X(4,  H1A, WV4(20), x4.x,x4.y,x4.z,x4.w); }
                { const float4 x4 = xw[21*nact]; DC1X(5,  H1A, WV4(21), x4.x,x4.y,x4.z,x4.w); }
                { const float4 x4 = xw[22*nact]; DC1X(6,  H1A, WV4(22), x4.x,x4.y,x4.z,x4.w); }
                { const float4 x4 = xw[23*nact]; const float4 wl = wlds[0][t];
                  DC1X(7, H1A, wl.x, wl.y, wl.z, wl.w, x4.x, x4.y, x4.z, x4.w); }
                { const float4 x4 = xw[24*nact]; const float4 wl = wlds[1][t];
                  DC1X(8, H1A, wl.x, wl.y, wl.z, wl.w, x4.x, x4.y, x4.z, x4.w); }
            }

            gAll[bx][t] = a0 + a0b;
            if (xtr && lane < nact) gX[bx][xu0 + lane] = xa0 + xa0b;

            // y-dot atomics for batch bx (reads shs[1][bx], stable this window)
            if (tA >= 2 && (tA - 2) % LSEQ == LSEQ - 1 && t < 100) {
                atomicAdd(&yacc[bx], sfcw[t] * shs[1][bx][t]);
            }
        }

        __syncthreads();
    }
}

extern "C" void kernel_launch(void* const* d_in, const int* in_sizes, int n_in,
                              void* d_out, int out_size, void* d_ws, size_t ws_size,
                              hipStream_t stream) {
    const float* X    = (const float*)d_in[0];
    const float* Wih0 = (const float*)d_in[1];
    const float* Whh0 = (const float*)d_in[2];
    const float* bih0 = (const float*)d_in[3];
    const float* bhh0 = (const float*)d_in[4];
    const float* Wih1 = (const float*)d_in[5];
    const float* Whh1 = (const float*)d_in[6];
    const float* bih1 = (const float*)d_in[7];
    const float* bhh1 = (const float*)d_in[8];
    const float* fcw  = (const float*)d_in[9];
    const float* fcb  = (const float*)d_in[10];
    float* out = (float*)d_out;
    float* wsT = (float*)d_ws;   // 4400 float4 = 70,400 B

    hipLaunchKernelGGL(prep_kernel, dim3((NX4 * 4 + 255) / 256), dim3(256), 0, stream,
                       Wih1, Whh1, wsT);
    hipLaunchKernelGGL(lstm_kernel, dim3(256), dim3(1024), 0, stream,
                       X, Wih0, Whh0, bih0, bhh0, Wih1, Whh1, bih1, bhh1,
                       fcw, fcb, wsT, out);
}